// Round 6
// baseline (535.726 us; speedup 1.0000x reference)
//
#include <hip/hip_runtime.h>
#include <math.h>

typedef __attribute__((ext_vector_type(8))) short short8;
typedef __attribute__((ext_vector_type(4))) float f32x4;
typedef __attribute__((ext_vector_type(4))) unsigned int uint4v;

#define HIDDEN 1024
#define QOUT 2048
#define KVOUT 1024
#define HD 128
#define TSEQ 2048

__device__ __forceinline__ float bf2f(unsigned short h) {
    union { unsigned int u; float f; } x; x.u = ((unsigned int)h) << 16; return x.f;
}
__device__ __forceinline__ unsigned short f2bf(float f) {
    union { float f; unsigned int u; } x; x.f = f;
    unsigned int r = (x.u + 0x7fffu + ((x.u >> 16) & 1u)) >> 16;
    return (unsigned short)r;
}
__device__ __forceinline__ unsigned int pk2bf(float lo, float hi) {
    return (unsigned int)f2bf(lo) | ((unsigned int)f2bf(hi) << 16);
}

// async global->LDS, 16B per lane; dest = wave-uniform base + lane*16
__device__ __forceinline__ void glds16(const unsigned short* g, unsigned short* l) {
    __builtin_amdgcn_global_load_lds(
        (const __attribute__((address_space(1))) unsigned int*)g,
        (__attribute__((address_space(3))) unsigned int*)l, 16, 0, 0);
}

// ---------------- cast x (fp32) -> bf16 ----------------
__global__ __launch_bounds__(256) void cast_f32_bf16(const float* __restrict__ in,
                                                     unsigned short* __restrict__ out, int n4) {
    int i = blockIdx.x * 256 + threadIdx.x;
    if (i >= n4) return;
    float4 v = *(const float4*)(in + (size_t)i * 4);
    unsigned short o[4] = {f2bf(v.x), f2bf(v.y), f2bf(v.z), f2bf(v.w)};
    *(unsigned long long*)(out + (size_t)i * 4) = *(unsigned long long*)o;
}

// ---------------- weight transpose: W (K x N) fp32 row-major -> Wt (N x K) bf16 ----------------
__global__ __launch_bounds__(256) void transpose_f32_bf16(const float* __restrict__ W,
                                                          unsigned short* __restrict__ Wt,
                                                          int K, int N) {
    __shared__ __attribute__((aligned(16))) unsigned short Ls[64 * 72];
    int ntiles = N >> 6;
    int kt = blockIdx.x / ntiles, nt = blockIdx.x - kt * ntiles;
    int k0 = kt * 64, n0 = nt * 64;
    int tid = threadIdx.x;
    for (int t = 0; t < 4; t++) {
        int idx = tid + t * 256;
        int r = idx >> 4, seg = idx & 15;
        float4 v = *(const float4*)(W + (size_t)(k0 + r) * N + n0 + seg * 4);
        int c = seg * 4;
        Ls[(c + 0) * 72 + r] = f2bf(v.x);
        Ls[(c + 1) * 72 + r] = f2bf(v.y);
        Ls[(c + 2) * 72 + r] = f2bf(v.z);
        Ls[(c + 3) * 72 + r] = f2bf(v.w);
    }
    __syncthreads();
    for (int t = 0; t < 2; t++) {
        int idx = tid + t * 256;
        int rr = idx >> 3, seg = idx & 7;
        uint4v v = *(const uint4v*)(Ls + rr * 72 + seg * 8);
        *(uint4v*)(Wt + (size_t)(n0 + rr) * K + k0 + seg * 8) = v;
    }
}

// ---------------- GEMM: C[M,N] = A[M,K](bf16) @ Bt[N,K]^T(bf16) ----------------
// glds16 staging with XOR chunk swizzle; transposed-acc (mfma(bf,af)) -> vector stores.
template <int OUT_BF16, int BN>
__global__ __launch_bounds__(256) void gemm_bt(const unsigned short* __restrict__ A,
                                               const unsigned short* __restrict__ Bt,
                                               void* __restrict__ Cout,
                                               int M, int N, int K) {
    constexpr int MT = (BN == 128) ? 4 : 2;
    __shared__ __attribute__((aligned(16))) unsigned short As[128 * 32];
    __shared__ __attribute__((aligned(16))) unsigned short Bs[BN * 32];
    const int tid = threadIdx.x;
    const int lane = tid & 63;
    const int warp = tid >> 6;
    const int ln = lane & 15;
    const int quad = lane >> 4;
    const int wm = (BN == 128) ? (warp >> 1) : warp;
    const int wn = (BN == 128) ? (warp & 1) : 0;
    const int m0 = blockIdx.y * 128;
    const int n0 = blockIdx.x * BN;

    const int srow = lane >> 2;
    const int schunk = (lane & 3) ^ (srow & 3);
    const unsigned short* Ag = A + (size_t)(m0 + warp * 16 + srow) * K + schunk * 8;
    const unsigned short* Bg = Bt + (size_t)(n0 + warp * 16 + srow) * K + schunk * 8;
    unsigned short* AsW = As + warp * 16 * 32;
    unsigned short* BsW = Bs + warp * 16 * 32;

    f32x4 acc[MT][4];
    for (int i = 0; i < MT; i++)
        for (int j = 0; j < 4; j++) acc[i][j] = (f32x4){0.f, 0.f, 0.f, 0.f};

    const int rq = quad ^ (ln & 3);   // swizzled read chunk
    for (int k0 = 0; k0 < K; k0 += 32) {
        __syncthreads();
        glds16(Ag + k0, AsW);
        glds16(Ag + (size_t)64 * K + k0, AsW + 64 * 32);
        glds16(Bg + k0, BsW);
        if (BN == 128) glds16(Bg + (size_t)64 * K + k0, BsW + 64 * 32);
        __syncthreads();
        short8 af[MT], bf[4];
        for (int mt = 0; mt < MT; mt++)
            af[mt] = *(const short8*)(As + (wm * (MT * 16) + mt * 16 + ln) * 32 + rq * 8);
        for (int nt = 0; nt < 4; nt++)
            bf[nt] = *(const short8*)(Bs + (wn * 64 + nt * 16 + ln) * 32 + rq * 8);
        // swapped operands: acc lane ln <-> output ROW, regs <-> 4 consecutive cols
        for (int mt = 0; mt < MT; mt++)
            for (int nt = 0; nt < 4; nt++)
                acc[mt][nt] = __builtin_amdgcn_mfma_f32_16x16x32_bf16(bf[nt], af[mt], acc[mt][nt], 0, 0, 0);
    }
    for (int mt = 0; mt < MT; mt++) {
        int row = m0 + wm * (MT * 16) + mt * 16 + ln;
        for (int nt = 0; nt < 4; nt++) {
            int colb = n0 + wn * 64 + nt * 16 + quad * 4;
            if (OUT_BF16) {
                unsigned long long pk =
                    (unsigned long long)pk2bf(acc[mt][nt][0], acc[mt][nt][1]) |
                    ((unsigned long long)pk2bf(acc[mt][nt][2], acc[mt][nt][3]) << 32);
                *(unsigned long long*)((unsigned short*)Cout + (size_t)row * N + colb) = pk;
            } else {
                *(f32x4*)((float*)Cout + (size_t)row * N + colb) = acc[mt][nt];
            }
        }
    }
}

// ---------------- fused per-head RMSNorm + RoPE for Q and K (bf16 QKV in) ----------------
__global__ __launch_bounds__(256) void norm_rope(const unsigned short* __restrict__ QKV,
                                                 const float* __restrict__ qw,
                                                 const float* __restrict__ kw,
                                                 unsigned short* __restrict__ Q,
                                                 unsigned short* __restrict__ Kb) {
    int warp = threadIdx.x >> 6;
    int lane = threadIdx.x & 63;
    int gid = blockIdx.x * 4 + warp;
    int tok = gid / 24;
    int slot = gid - tok * 24;
    int b = tok >> 11, t = tok & 2047;
    const float* w;
    unsigned short* dst;
    int col0;
    if (slot < 16) {
        col0 = slot * HD;
        dst = Q + ((size_t)(b * 16 + slot) * TSEQ + t) * HD;
        w = qw;
    } else {
        int hk = slot - 16;
        col0 = QOUT + hk * HD;
        dst = Kb + ((size_t)(b * 8 + hk) * TSEQ + t) * HD;
        w = kw;
    }
    const unsigned short* row = QKV + (size_t)tok * 4096 + col0;
    float e0 = bf2f(row[lane]), e1 = bf2f(row[lane + 64]);
    float ss = e0 * e0 + e1 * e1;
    for (int off = 1; off < 64; off <<= 1) ss += __shfl_xor(ss, off);
    float rr = rsqrtf(ss * (1.0f / 128.0f) + 1e-6f);
    float n0 = e0 * rr * w[lane];
    float n1 = e1 * rr * w[lane + 64];
    float invf = __builtin_exp2f(-(float)lane * 0.20762050593045951f);
    float ang = (float)t * invf;
    float sf, cf;
    __sincosf(ang, &sf, &cf);
    float o0 = n0 * cf - n1 * sf;
    float o1 = n1 * cf + n0 * sf;
    dst[lane] = f2bf(o0);
    dst[lane + 64] = f2bf(o1);
}

// ---------------- V transpose: QKV v-cols (bf16) -> Vt (b,hk,d,t) bf16 ----------------
__global__ __launch_bounds__(256) void v_transpose(const unsigned short* __restrict__ QKV,
                                                   unsigned short* __restrict__ Vt) {
    __shared__ __attribute__((aligned(16))) unsigned short Ls[128 * 72];
    int bid = blockIdx.x;
    int tt = bid & 31, hk = (bid >> 5) & 7, b = bid >> 8;
    int t0 = tt * 64;
    int tid = threadIdx.x;
    const unsigned short* base = QKV + (size_t)(b * 2048 + t0) * 4096 + 3072 + hk * 128;
    for (int i = 0; i < 4; i++) {
        int idx = tid + i * 256;
        int r = idx >> 4, seg = idx & 15;
        uint4v v = *(const uint4v*)(base + (size_t)r * 4096 + seg * 8);
        unsigned short* pv = (unsigned short*)&v;
        int d = seg * 8;
        for (int jj = 0; jj < 8; jj++) Ls[(d + jj) * 72 + r] = pv[jj];
    }
    __syncthreads();
    unsigned short* out = Vt + (size_t)(b * 8 + hk) * 128 * 2048;
    for (int i = 0; i < 4; i++) {
        int idx = tid + i * 256;
        int d = idx >> 3, seg = idx & 7;
        uint4v v = *(const uint4v*)(Ls + d * 72 + seg * 8);
        *(uint4v*)(out + (size_t)d * 2048 + t0 + seg * 8) = v;
    }
}

// ---------------- flash attention v5 ----------------
// grid (16 p, 32 b*h), 256 thr. Wave owns 16 rows of tile p (strip 0, active j<=p)
// and 16 rows of tile 31-p (strip 1, always active). kf/vf shared across strips;
// P via per-wave LDS; PV operand-swapped so O has q=lane (no alpha/inv shuffles).
__global__ __launch_bounds__(256, 2) void attn(const unsigned short* __restrict__ Q,
                                               const unsigned short* __restrict__ Kg,
                                               const unsigned short* __restrict__ Vt,
                                               unsigned short* __restrict__ Og) {
    __shared__ __attribute__((aligned(16))) unsigned short Ks[64 * 128];  // swizzled (kv, d)
    __shared__ __attribute__((aligned(16))) unsigned short Vs[128 * 64];  // swizzled (d, kv)
    __shared__ __attribute__((aligned(16))) unsigned short Ps[4][16 * 72];
    const int p = blockIdx.x;
    const int bh = blockIdx.y;
    const int b = bh >> 4, h = bh & 15, hk = h >> 1;
    const int tid = threadIdx.x;
    const int warp = tid >> 6, lane = tid & 63, ln = lane & 15, quad = lane >> 4;
    const int strip[2] = { p * 64 + warp * 16, (31 - p) * 64 + warp * 16 };
    const int jdiag[2] = { p, 31 - p };

    const unsigned short* Kbase = Kg + (size_t)(b * 8 + hk) * TSEQ * HD;
    const unsigned short* Vbase = Vt + (size_t)(b * 8 + hk) * HD * TSEQ;
    const unsigned short* Qh = Q + (size_t)(b * 16 + h) * TSEQ * HD;

    short8 qf[2][4];
    for (int st = 0; st < 2; st++)
        for (int kt = 0; kt < 4; kt++)
            qf[st][kt] = *(const short8*)(Qh + (size_t)(strip[st] + ln) * HD + kt * 32 + quad * 8);

    f32x4 o[2][8];
    for (int st = 0; st < 2; st++)
        for (int ot = 0; ot < 8; ot++) o[st][ot] = (f32x4){0.f, 0.f, 0.f, 0.f};
    float m_[2] = {-1e30f, -1e30f}, l_[2] = {0.f, 0.f};

    const int kr = lane >> 4;
    const int kc = lane & 15;
    const int vr = lane >> 3;
    const int vc = lane & 7;

    const float kscale = 0.12750580997495268f;  // (1/sqrt(128)) * log2(e)
    const int nT = 32 - p;
    for (int j = 0; j < nT; j++) {
        const int j0 = j * 64;
        __syncthreads();
        for (int c = 0; c < 4; c++) {   // K: LDS[r][c] = K[r][c ^ (r&15)]
            int row = warp * 16 + c * 4 + kr;
            glds16(Kbase + (size_t)(j0 + row) * HD + ((kc ^ (row & 15)) * 8),
                   Ks + (warp * 16 + c * 4) * 128);
        }
        for (int c = 0; c < 4; c++) {   // V^T: LDS[d][c] = V[d][c ^ (d&7)]
            int d = warp * 32 + c * 8 + vr;
            glds16(Vbase + (size_t)d * TSEQ + j0 + ((vc ^ (d & 7)) * 8),
                   Vs + (warp * 32 + c * 8) * 64);
        }
        __syncthreads();
        const bool act0 = (j <= jdiag[0]);
        // ---- QK^T for both strips, kf shared ----
        f32x4 s[2][4];
        for (int kb = 0; kb < 4; kb++) {
            s[0][kb] = (f32x4){0.f, 0.f, 0.f, 0.f};
            s[1][kb] = (f32x4){0.f, 0.f, 0.f, 0.f};
        }
        for (int kt = 0; kt < 4; kt++) {
            short8 kf[4];
            for (int kb = 0; kb < 4; kb++)
                kf[kb] = *(const short8*)(Ks + (kb * 16 + ln) * 128 + (((kt * 4 + quad) ^ ln) * 8));
            for (int kb = 0; kb < 4; kb++)
                s[1][kb] = __builtin_amdgcn_mfma_f32_16x16x32_bf16(kf[kb], qf[1][kt], s[1][kb], 0, 0, 0);
            if (act0)
                for (int kb = 0; kb < 4; kb++)
                    s[0][kb] = __builtin_amdgcn_mfma_f32_16x16x32_bf16(kf[kb], qf[0][kt], s[0][kb], 0, 0, 0);
        }
        // ---- softmax + P staging per strip ----
        short8 pf[2][2];
        float al[2] = {1.f, 1.f};
        for (int st = (act0 ? 0 : 1); st < 2; st++) {
            float mx = -1e30f;
            if (j == jdiag[st]) {
                const int qloc = warp * 16 + ln;
                for (int kb = 0; kb < 4; kb++)
                    for (int r = 0; r < 4; r++) {
                        int kvloc = kb * 16 + quad * 4 + r;
                        float v = s[st][kb][r] * kscale;
                        v = (kvloc > qloc) ? -1e30f : v;
                        s[st][kb][r] = v;
                        mx = fmaxf(mx, v);
                    }
            } else {
                for (int kb = 0; kb < 4; kb++)
                    for (int r = 0; r < 4; r++) {
                        float v = s[st][kb][r] * kscale;
                        s[st][kb][r] = v;
                        mx = fmaxf(mx, v);
                    }
            }
            mx = fmaxf(mx, __shfl_xor(mx, 16));
            mx = fmaxf(mx, __shfl_xor(mx, 32));
            float mn = fmaxf(m_[st], mx);
            al[st] = __builtin_exp2f(m_[st] - mn);
            float sum = 0.f;
            for (int kb = 0; kb < 4; kb++)
                for (int r = 0; r < 4; r++) {
                    float pv = __builtin_exp2f(s[st][kb][r] - mn);
                    s[st][kb][r] = pv;
                    sum += pv;
                }
            sum += __shfl_xor(sum, 16);
            sum += __shfl_xor(sum, 32);
            m_[st] = mn;
            l_[st] = l_[st] * al[st] + sum;
            // write packed P row (q=ln), then read back in A/B-operand layout
            for (int kb = 0; kb < 4; kb++) {
                unsigned long long pk =
                    (unsigned long long)pk2bf(s[st][kb][0], s[st][kb][1]) |
                    ((unsigned long long)pk2bf(s[st][kb][2], s[st][kb][3]) << 32);
                *(unsigned long long*)(&Ps[warp][ln * 72 + kb * 16 + quad * 4]) = pk;
            }
            pf[st][0] = *(const short8*)(&Ps[warp][ln * 72 + quad * 8]);
            pf[st][1] = *(const short8*)(&Ps[warp][ln * 72 + 32 + quad * 8]);
        }
        // ---- rescale O (per-lane alpha, q = ln) ----
        if (act0 && __any(al[0] != 1.0f))
            for (int ot = 0; ot < 8; ot++)
                for (int r = 0; r < 4; r++) o[0][ot][r] *= al[0];
        if (__any(al[1] != 1.0f))
            for (int ot = 0; ot < 8; ot++)
                for (int r = 0; r < 4; r++) o[1][ot][r] *= al[1];
        // ---- PV, vf shared across strips; operand-swapped (O: col=q=ln, rows=d) ----
        for (int ot = 0; ot < 8; ot++) {
            short8 vf0 = *(const short8*)(Vs + (ot * 16 + ln) * 64 + ((quad ^ (ln & 7)) * 8));
            short8 vf1 = *(const short8*)(Vs + (ot * 16 + ln) * 64 + (((4 + quad) ^ (ln & 7)) * 8));
            o[1][ot] = __builtin_amdgcn_mfma_f32_16x16x32_bf16(vf0, pf[1][0], o[1][ot], 0, 0, 0);
            o[1][ot] = __builtin_amdgcn_mfma_f32_16x16x32_bf16(vf1, pf[1][1], o[1][ot], 0, 0, 0);
            if (act0) {
                o[0][ot] = __builtin_amdgcn_mfma_f32_16x16x32_bf16(vf0, pf[0][0], o[0][ot], 0, 0, 0);
                o[0][ot] = __builtin_amdgcn_mfma_f32_16x16x32_bf16(vf1, pf[0][1], o[0][ot], 0, 0, 0);
            }
        }
    }
    // epilogue: lane has q = strip+ln; regs are 4 consecutive d -> 8B stores
    for (int st = 0; st < 2; st++) {
        float inv = 1.0f / l_[st];
        size_t rowoff = ((size_t)(b * TSEQ + strip[st] + ln)) * QOUT + h * 128 + quad * 4;
        for (int ot = 0; ot < 8; ot++) {
            unsigned long long pk =
                (unsigned long long)pk2bf(o[st][ot][0] * inv, o[st][ot][1] * inv) |
                ((unsigned long long)pk2bf(o[st][ot][2] * inv, o[st][ot][3] * inv) << 32);
            *(unsigned long long*)(Og + rowoff + ot * 16) = pk;
        }
    }
}

extern "C" void kernel_launch(void* const* d_in, const int* in_sizes, int n_in,
                              void* d_out, int out_size, void* d_ws, size_t ws_size,
                              hipStream_t stream) {
    (void)in_sizes; (void)n_in; (void)out_size;
    const float* x  = (const float*)d_in[0];
    const float* Wq = (const float*)d_in[1];
    const float* Wk = (const float*)d_in[2];
    const float* Wv = (const float*)d_in[3];
    const float* Wo = (const float*)d_in[4];
    const float* qw = (const float*)d_in[5];
    const float* kw = (const float*)d_in[6];

    char* ws = (char*)d_ws;
    const size_t MB = 1024 * 1024;
    unsigned short* Wt   = (unsigned short*)(ws);            // 8 MB
    unsigned short* Wot  = (unsigned short*)(ws + 8 * MB);   // 4 MB
    unsigned short* QKVb = (unsigned short*)(ws + 12 * MB);  // 32 MB (bf16)
    unsigned short* xb   = (unsigned short*)(ws + 44 * MB);  // 8 MB
    unsigned short* Qb   = (unsigned short*)(ws + 52 * MB);  // 16 MB
    unsigned short* Kb   = (unsigned short*)(ws + 68 * MB);  // 8 MB
    unsigned short* Vtb  = (unsigned short*)(ws + 76 * MB);  // 8 MB
    unsigned short* Ob   = (unsigned short*)(ws + 84 * MB);  // 16 MB
    if (ws_size < 100 * MB) return;

    cast_f32_bf16<<<dim3(4096), 256, 0, stream>>>(x, xb, 1048576);
    transpose_f32_bf16<<<dim3(512), 256, 0, stream>>>(Wq, Wt, 1024, 2048);
    transpose_f32_bf16<<<dim3(256), 256, 0, stream>>>(Wk, Wt + (size_t)2048 * 1024, 1024, 1024);
    transpose_f32_bf16<<<dim3(256), 256, 0, stream>>>(Wv, Wt + (size_t)3072 * 1024, 1024, 1024);
    transpose_f32_bf16<<<dim3(512), 256, 0, stream>>>(Wo, Wot, 2048, 1024);
    gemm_bt<1, 128><<<dim3(32, 32), 256, 0, stream>>>(xb, Wt, QKVb, 4096, 4096, 1024);
    norm_rope<<<dim3(24576), 256, 0, stream>>>(QKVb, qw, kw, Qb, Kb);
    v_transpose<<<dim3(512), 256, 0, stream>>>(QKVb, Vtb);
    attn<<<dim3(16, 32), 256, 0, stream>>>(Qb, Kb, Vtb, Ob);
    gemm_bt<0, 64><<<dim3(16, 32), 256, 0, stream>>>(Ob, Wot, (float*)d_out, 4096, 1024, 2048);
}

// Round 7
// 300.897 us; speedup vs baseline: 1.7804x; 1.7804x over previous
//
#include <hip/hip_runtime.h>
#include <math.h>

typedef __attribute__((ext_vector_type(8))) short short8;
typedef __attribute__((ext_vector_type(4))) float f32x4;
typedef __attribute__((ext_vector_type(4))) unsigned int uint4v;

#define HIDDEN 1024
#define QOUT 2048
#define KVOUT 1024
#define HD 128
#define TSEQ 2048

__device__ __forceinline__ float bf2f(unsigned short h) {
    union { unsigned int u; float f; } x; x.u = ((unsigned int)h) << 16; return x.f;
}
__device__ __forceinline__ unsigned short f2bf(float f) {
    union { float f; unsigned int u; } x; x.f = f;
    unsigned int r = (x.u + 0x7fffu + ((x.u >> 16) & 1u)) >> 16;
    return (unsigned short)r;
}
__device__ __forceinline__ unsigned int pk2bf(float lo, float hi) {
    return (unsigned int)f2bf(lo) | ((unsigned int)f2bf(hi) << 16);
}

// async global->LDS, 16B per lane; dest = wave-uniform base + lane*16
__device__ __forceinline__ void glds16(const unsigned short* g, unsigned short* l) {
    __builtin_amdgcn_global_load_lds(
        (const __attribute__((address_space(1))) unsigned int*)g,
        (__attribute__((address_space(3))) unsigned int*)l, 16, 0, 0);
}

// ---------------- cast x (fp32) -> bf16 ----------------
__global__ __launch_bounds__(256) void cast_f32_bf16(const float* __restrict__ in,
                                                     unsigned short* __restrict__ out, int n4) {
    int i = blockIdx.x * 256 + threadIdx.x;
    if (i >= n4) return;
    float4 v = *(const float4*)(in + (size_t)i * 4);
    unsigned short o[4] = {f2bf(v.x), f2bf(v.y), f2bf(v.z), f2bf(v.w)};
    *(unsigned long long*)(out + (size_t)i * 4) = *(unsigned long long*)o;
}

// ---------------- weight transpose: W (K x N) fp32 row-major -> Wt (N x K) bf16 ----------------
__global__ __launch_bounds__(256) void transpose_f32_bf16(const float* __restrict__ W,
                                                          unsigned short* __restrict__ Wt,
                                                          int K, int N) {
    __shared__ __attribute__((aligned(16))) unsigned short Ls[64 * 72];
    int ntiles = N >> 6;
    int kt = blockIdx.x / ntiles, nt = blockIdx.x - kt * ntiles;
    int k0 = kt * 64, n0 = nt * 64;
    int tid = threadIdx.x;
    for (int t = 0; t < 4; t++) {
        int idx = tid + t * 256;
        int r = idx >> 4, seg = idx & 15;
        float4 v = *(const float4*)(W + (size_t)(k0 + r) * N + n0 + seg * 4);
        int c = seg * 4;
        Ls[(c + 0) * 72 + r] = f2bf(v.x);
        Ls[(c + 1) * 72 + r] = f2bf(v.y);
        Ls[(c + 2) * 72 + r] = f2bf(v.z);
        Ls[(c + 3) * 72 + r] = f2bf(v.w);
    }
    __syncthreads();
    for (int t = 0; t < 2; t++) {
        int idx = tid + t * 256;
        int rr = idx >> 3, seg = idx & 7;
        uint4v v = *(const uint4v*)(Ls + rr * 72 + seg * 8);
        *(uint4v*)(Wt + (size_t)(n0 + rr) * K + k0 + seg * 8) = v;
    }
}

// ---------------- GEMM: C[M,N] = A[M,K](bf16) @ Bt[N,K]^T(bf16) ----------------
// glds16 staging with XOR chunk swizzle; transposed-acc (mfma(bf,af)) -> vector stores.
template <int OUT_BF16, int BN>
__global__ __launch_bounds__(256) void gemm_bt(const unsigned short* __restrict__ A,
                                               const unsigned short* __restrict__ Bt,
                                               void* __restrict__ Cout,
                                               int M, int N, int K) {
    constexpr int MT = (BN == 128) ? 4 : 2;
    __shared__ __attribute__((aligned(16))) unsigned short As[128 * 32];
    __shared__ __attribute__((aligned(16))) unsigned short Bs[BN * 32];
    const int tid = threadIdx.x;
    const int lane = tid & 63;
    const int warp = tid >> 6;
    const int ln = lane & 15;
    const int quad = lane >> 4;
    const int wm = (BN == 128) ? (warp >> 1) : warp;
    const int wn = (BN == 128) ? (warp & 1) : 0;
    const int m0 = blockIdx.y * 128;
    const int n0 = blockIdx.x * BN;

    const int srow = lane >> 2;
    const int schunk = (lane & 3) ^ (srow & 3);
    const unsigned short* Ag = A + (size_t)(m0 + warp * 16 + srow) * K + schunk * 8;
    const unsigned short* Bg = Bt + (size_t)(n0 + warp * 16 + srow) * K + schunk * 8;
    unsigned short* AsW = As + warp * 16 * 32;
    unsigned short* BsW = Bs + warp * 16 * 32;

    f32x4 acc[MT][4];
    for (int i = 0; i < MT; i++)
        for (int j = 0; j < 4; j++) acc[i][j] = (f32x4){0.f, 0.f, 0.f, 0.f};

    const int rq = quad ^ (ln & 3);   // swizzled read chunk
    for (int k0 = 0; k0 < K; k0 += 32) {
        __syncthreads();
        glds16(Ag + k0, AsW);
        glds16(Ag + (size_t)64 * K + k0, AsW + 64 * 32);
        glds16(Bg + k0, BsW);
        if (BN == 128) glds16(Bg + (size_t)64 * K + k0, BsW + 64 * 32);
        __syncthreads();
        short8 af[MT], bf[4];
        for (int mt = 0; mt < MT; mt++)
            af[mt] = *(const short8*)(As + (wm * (MT * 16) + mt * 16 + ln) * 32 + rq * 8);
        for (int nt = 0; nt < 4; nt++)
            bf[nt] = *(const short8*)(Bs + (wn * 64 + nt * 16 + ln) * 32 + rq * 8);
        // swapped operands: acc lane ln <-> output ROW, regs <-> 4 consecutive cols
        for (int mt = 0; mt < MT; mt++)
            for (int nt = 0; nt < 4; nt++)
                acc[mt][nt] = __builtin_amdgcn_mfma_f32_16x16x32_bf16(bf[nt], af[mt], acc[mt][nt], 0, 0, 0);
    }
    for (int mt = 0; mt < MT; mt++) {
        int row = m0 + wm * (MT * 16) + mt * 16 + ln;
        for (int nt = 0; nt < 4; nt++) {
            int colb = n0 + wn * 64 + nt * 16 + quad * 4;
            if (OUT_BF16) {
                unsigned long long pk =
                    (unsigned long long)pk2bf(acc[mt][nt][0], acc[mt][nt][1]) |
                    ((unsigned long long)pk2bf(acc[mt][nt][2], acc[mt][nt][3]) << 32);
                *(unsigned long long*)((unsigned short*)Cout + (size_t)row * N + colb) = pk;
            } else {
                *(f32x4*)((float*)Cout + (size_t)row * N + colb) = acc[mt][nt];
            }
        }
    }
}

// ---------------- fused per-head RMSNorm + RoPE for Q and K (bf16 QKV in) ----------------
__global__ __launch_bounds__(256) void norm_rope(const unsigned short* __restrict__ QKV,
                                                 const float* __restrict__ qw,
                                                 const float* __restrict__ kw,
                                                 unsigned short* __restrict__ Q,
                                                 unsigned short* __restrict__ Kb) {
    int warp = threadIdx.x >> 6;
    int lane = threadIdx.x & 63;
    int gid = blockIdx.x * 4 + warp;
    int tok = gid / 24;
    int slot = gid - tok * 24;
    int b = tok >> 11, t = tok & 2047;
    const float* w;
    unsigned short* dst;
    int col0;
    if (slot < 16) {
        col0 = slot * HD;
        dst = Q + ((size_t)(b * 16 + slot) * TSEQ + t) * HD;
        w = qw;
    } else {
        int hk = slot - 16;
        col0 = QOUT + hk * HD;
        dst = Kb + ((size_t)(b * 8 + hk) * TSEQ + t) * HD;
        w = kw;
    }
    const unsigned short* row = QKV + (size_t)tok * 4096 + col0;
    float e0 = bf2f(row[lane]), e1 = bf2f(row[lane + 64]);
    float ss = e0 * e0 + e1 * e1;
    for (int off = 1; off < 64; off <<= 1) ss += __shfl_xor(ss, off);
    float rr = rsqrtf(ss * (1.0f / 128.0f) + 1e-6f);
    float n0 = e0 * rr * w[lane];
    float n1 = e1 * rr * w[lane + 64];
    float invf = __builtin_exp2f(-(float)lane * 0.20762050593045951f);
    float ang = (float)t * invf;
    float sf, cf;
    __sincosf(ang, &sf, &cf);
    float o0 = n0 * cf - n1 * sf;
    float o1 = n1 * cf + n0 * sf;
    dst[lane] = f2bf(o0);
    dst[lane + 64] = f2bf(o1);
}

// ---------------- V transpose: QKV v-cols (bf16) -> Vt (b,hk,d,t) bf16 ----------------
__global__ __launch_bounds__(256) void v_transpose(const unsigned short* __restrict__ QKV,
                                                   unsigned short* __restrict__ Vt) {
    __shared__ __attribute__((aligned(16))) unsigned short Ls[128 * 72];
    int bid = blockIdx.x;
    int tt = bid & 31, hk = (bid >> 5) & 7, b = bid >> 8;
    int t0 = tt * 64;
    int tid = threadIdx.x;
    const unsigned short* base = QKV + (size_t)(b * 2048 + t0) * 4096 + 3072 + hk * 128;
    for (int i = 0; i < 4; i++) {
        int idx = tid + i * 256;
        int r = idx >> 4, seg = idx & 15;
        uint4v v = *(const uint4v*)(base + (size_t)r * 4096 + seg * 8);
        unsigned short* pv = (unsigned short*)&v;
        int d = seg * 8;
        for (int jj = 0; jj < 8; jj++) Ls[(d + jj) * 72 + r] = pv[jj];
    }
    __syncthreads();
    unsigned short* out = Vt + (size_t)(b * 8 + hk) * 128 * 2048;
    for (int i = 0; i < 4; i++) {
        int idx = tid + i * 256;
        int d = idx >> 3, seg = idx & 7;
        uint4v v = *(const uint4v*)(Ls + d * 72 + seg * 8);
        *(uint4v*)(out + (size_t)d * 2048 + t0 + seg * 8) = v;
    }
}

// ---------------- flash attention v6 (v5 structure, spill-free) ----------------
// grid (16 p, 32 b*h), 256 thr. Wave owns 16 rows of tile p (strip 0, active j<=p)
// and 16 rows of tile 31-p (strip 1, always active). kf/vf shared across strips;
// P via per-wave LDS; PV operand-swapped so O has q=lane. ALL register arrays
// statically indexed (constant-bound unrolled loops) -- dynamic indexing spills.
__global__ __launch_bounds__(256, 2) void attn(const unsigned short* __restrict__ Q,
                                               const unsigned short* __restrict__ Kg,
                                               const unsigned short* __restrict__ Vt,
                                               unsigned short* __restrict__ Og) {
    __shared__ __attribute__((aligned(16))) unsigned short Ks[64 * 128];  // swizzled (kv, d)
    __shared__ __attribute__((aligned(16))) unsigned short Vs[128 * 64];  // swizzled (d, kv)
    __shared__ __attribute__((aligned(16))) unsigned short Ps[4][16 * 72];
    const int p = blockIdx.x;
    const int bh = blockIdx.y;
    const int b = bh >> 4, h = bh & 15, hk = h >> 1;
    const int tid = threadIdx.x;
    const int warp = tid >> 6, lane = tid & 63, ln = lane & 15, quad = lane >> 4;
    const int strip[2] = { p * 64 + warp * 16, (31 - p) * 64 + warp * 16 };
    const int jdiag[2] = { p, 31 - p };

    const unsigned short* Kbase = Kg + (size_t)(b * 8 + hk) * TSEQ * HD;
    const unsigned short* Vbase = Vt + (size_t)(b * 8 + hk) * HD * TSEQ;
    const unsigned short* Qh = Q + (size_t)(b * 16 + h) * TSEQ * HD;

    short8 qf[2][4];
#pragma unroll
    for (int st = 0; st < 2; st++)
#pragma unroll
        for (int kt = 0; kt < 4; kt++)
            qf[st][kt] = *(const short8*)(Qh + (size_t)(strip[st] + ln) * HD + kt * 32 + quad * 8);

    f32x4 o[2][8];
#pragma unroll
    for (int st = 0; st < 2; st++)
#pragma unroll
        for (int ot = 0; ot < 8; ot++) o[st][ot] = (f32x4){0.f, 0.f, 0.f, 0.f};
    float m_[2] = {-1e30f, -1e30f}, l_[2] = {0.f, 0.f};

    const int kr = lane >> 4;
    const int kc = lane & 15;
    const int vr = lane >> 3;
    const int vc = lane & 7;

    const float kscale = 0.12750580997495268f;  // (1/sqrt(128)) * log2(e)
    const int nT = 32 - p;
    for (int j = 0; j < nT; j++) {
        const int j0 = j * 64;
        __syncthreads();
#pragma unroll
        for (int c = 0; c < 4; c++) {   // K: LDS[r][c] = K[r][c ^ (r&15)]
            int row = warp * 16 + c * 4 + kr;
            glds16(Kbase + (size_t)(j0 + row) * HD + ((kc ^ (row & 15)) * 8),
                   Ks + (warp * 16 + c * 4) * 128);
        }
#pragma unroll
        for (int c = 0; c < 4; c++) {   // V^T: LDS[d][c] = V[d][c ^ (d&7)]
            int d = warp * 32 + c * 8 + vr;
            glds16(Vbase + (size_t)d * TSEQ + j0 + ((vc ^ (d & 7)) * 8),
                   Vs + (warp * 32 + c * 8) * 64);
        }
        __syncthreads();
        const bool act0 = (j <= jdiag[0]);
        // ---- QK^T for both strips, kf shared ----
        f32x4 s[2][4];
#pragma unroll
        for (int kb = 0; kb < 4; kb++) {
            s[0][kb] = (f32x4){0.f, 0.f, 0.f, 0.f};
            s[1][kb] = (f32x4){0.f, 0.f, 0.f, 0.f};
        }
#pragma unroll
        for (int kt = 0; kt < 4; kt++) {
            short8 kf[4];
#pragma unroll
            for (int kb = 0; kb < 4; kb++)
                kf[kb] = *(const short8*)(Ks + (kb * 16 + ln) * 128 + (((kt * 4 + quad) ^ ln) * 8));
#pragma unroll
            for (int kb = 0; kb < 4; kb++)
                s[1][kb] = __builtin_amdgcn_mfma_f32_16x16x32_bf16(kf[kb], qf[1][kt], s[1][kb], 0, 0, 0);
            if (act0)
#pragma unroll
                for (int kb = 0; kb < 4; kb++)
                    s[0][kb] = __builtin_amdgcn_mfma_f32_16x16x32_bf16(kf[kb], qf[0][kt], s[0][kb], 0, 0, 0);
        }
        // ---- softmax + P staging per strip (CONSTANT loop bounds; st==0 guarded inside) ----
        short8 pf[2][2];
        float al[2] = {1.f, 1.f};
#pragma unroll
        for (int st = 0; st < 2; st++) {
            if (st == 0 && !act0) continue;
            float mx = -1e30f;
            if (j == jdiag[st]) {
                const int qloc = warp * 16 + ln;
#pragma unroll
                for (int kb = 0; kb < 4; kb++)
#pragma unroll
                    for (int r = 0; r < 4; r++) {
                        int kvloc = kb * 16 + quad * 4 + r;
                        float v = s[st][kb][r] * kscale;
                        v = (kvloc > qloc) ? -1e30f : v;
                        s[st][kb][r] = v;
                        mx = fmaxf(mx, v);
                    }
            } else {
#pragma unroll
                for (int kb = 0; kb < 4; kb++)
#pragma unroll
                    for (int r = 0; r < 4; r++) {
                        float v = s[st][kb][r] * kscale;
                        s[st][kb][r] = v;
                        mx = fmaxf(mx, v);
                    }
            }
            mx = fmaxf(mx, __shfl_xor(mx, 16));
            mx = fmaxf(mx, __shfl_xor(mx, 32));
            float mn = fmaxf(m_[st], mx);
            al[st] = __builtin_exp2f(m_[st] - mn);
            float sum = 0.f;
#pragma unroll
            for (int kb = 0; kb < 4; kb++)
#pragma unroll
                for (int r = 0; r < 4; r++) {
                    float pv = __builtin_exp2f(s[st][kb][r] - mn);
                    s[st][kb][r] = pv;
                    sum += pv;
                }
            sum += __shfl_xor(sum, 16);
            sum += __shfl_xor(sum, 32);
            m_[st] = mn;
            l_[st] = l_[st] * al[st] + sum;
            // write packed P row (q=ln), then read back in A/B-operand layout
#pragma unroll
            for (int kb = 0; kb < 4; kb++) {
                unsigned long long pk =
                    (unsigned long long)pk2bf(s[st][kb][0], s[st][kb][1]) |
                    ((unsigned long long)pk2bf(s[st][kb][2], s[st][kb][3]) << 32);
                *(unsigned long long*)(&Ps[warp][ln * 72 + kb * 16 + quad * 4]) = pk;
            }
            pf[st][0] = *(const short8*)(&Ps[warp][ln * 72 + quad * 8]);
            pf[st][1] = *(const short8*)(&Ps[warp][ln * 72 + 32 + quad * 8]);
        }
        // ---- rescale O (per-lane alpha, q = ln) ----
        if (act0 && __any(al[0] != 1.0f))
#pragma unroll
            for (int ot = 0; ot < 8; ot++)
#pragma unroll
                for (int r = 0; r < 4; r++) o[0][ot][r] *= al[0];
        if (__any(al[1] != 1.0f))
#pragma unroll
            for (int ot = 0; ot < 8; ot++)
#pragma unroll
                for (int r = 0; r < 4; r++) o[1][ot][r] *= al[1];
        // ---- PV, vf shared across strips; operand-swapped (O: col=q=ln, rows=d) ----
#pragma unroll
        for (int ot = 0; ot < 8; ot++) {
            short8 vf0 = *(const short8*)(Vs + (ot * 16 + ln) * 64 + ((quad ^ (ln & 7)) * 8));
            short8 vf1 = *(const short8*)(Vs + (ot * 16 + ln) * 64 + (((4 + quad) ^ (ln & 7)) * 8));
            o[1][ot] = __builtin_amdgcn_mfma_f32_16x16x32_bf16(vf0, pf[1][0], o[1][ot], 0, 0, 0);
            o[1][ot] = __builtin_amdgcn_mfma_f32_16x16x32_bf16(vf1, pf[1][1], o[1][ot], 0, 0, 0);
            if (act0) {
                o[0][ot] = __builtin_amdgcn_mfma_f32_16x16x32_bf16(vf0, pf[0][0], o[0][ot], 0, 0, 0);
                o[0][ot] = __builtin_amdgcn_mfma_f32_16x16x32_bf16(vf1, pf[0][1], o[0][ot], 0, 0, 0);
            }
        }
    }
    // epilogue: lane has q = strip+ln; regs are 4 consecutive d -> 8B stores
#pragma unroll
    for (int st = 0; st < 2; st++) {
        float inv = 1.0f / l_[st];
        size_t rowoff = ((size_t)(b * TSEQ + strip[st] + ln)) * QOUT + h * 128 + quad * 4;
#pragma unroll
        for (int ot = 0; ot < 8; ot++) {
            unsigned long long pk =
                (unsigned long long)pk2bf(o[st][ot][0] * inv, o[st][ot][1] * inv) |
                ((unsigned long long)pk2bf(o[st][ot][2] * inv, o[st][ot][3] * inv) << 32);
            *(unsigned long long*)(Og + rowoff + ot * 16) = pk;
        }
    }
}

extern "C" void kernel_launch(void* const* d_in, const int* in_sizes, int n_in,
                              void* d_out, int out_size, void* d_ws, size_t ws_size,
                              hipStream_t stream) {
    (void)in_sizes; (void)n_in; (void)out_size;
    const float* x  = (const float*)d_in[0];
    const float* Wq = (const float*)d_in[1];
    const float* Wk = (const float*)d_in[2];
    const float* Wv = (const float*)d_in[3];
    const float* Wo = (const float*)d_in[4];
    const float* qw = (const float*)d_in[5];
    const float* kw = (const float*)d_in[6];

    char* ws = (char*)d_ws;
    const size_t MB = 1024 * 1024;
    unsigned short* Wt   = (unsigned short*)(ws);            // 8 MB
    unsigned short* Wot  = (unsigned short*)(ws + 8 * MB);   // 4 MB
    unsigned short* QKVb = (unsigned short*)(ws + 12 * MB);  // 32 MB (bf16)
    unsigned short* xb   = (unsigned short*)(ws + 44 * MB);  // 8 MB
    unsigned short* Qb   = (unsigned short*)(ws + 52 * MB);  // 16 MB
    unsigned short* Kb   = (unsigned short*)(ws + 68 * MB);  // 8 MB
    unsigned short* Vtb  = (unsigned short*)(ws + 76 * MB);  // 8 MB
    unsigned short* Ob   = (unsigned short*)(ws + 84 * MB);  // 16 MB
    if (ws_size < 100 * MB) return;

    cast_f32_bf16<<<dim3(4096), 256, 0, stream>>>(x, xb, 1048576);
    transpose_f32_bf16<<<dim3(512), 256, 0, stream>>>(Wq, Wt, 1024, 2048);
    transpose_f32_bf16<<<dim3(256), 256, 0, stream>>>(Wk, Wt + (size_t)2048 * 1024, 1024, 1024);
    transpose_f32_bf16<<<dim3(256), 256, 0, stream>>>(Wv, Wt + (size_t)3072 * 1024, 1024, 1024);
    transpose_f32_bf16<<<dim3(512), 256, 0, stream>>>(Wo, Wot, 2048, 1024);
    gemm_bt<1, 128><<<dim3(32, 32), 256, 0, stream>>>(xb, Wt, QKVb, 4096, 4096, 1024);
    norm_rope<<<dim3(24576), 256, 0, stream>>>(QKVb, qw, kw, Qb, Kb);
    v_transpose<<<dim3(512), 256, 0, stream>>>(QKVb, Vtb);
    attn<<<dim3(16, 32), 256, 0, stream>>>(Qb, Kb, Vtb, Ob);
    gemm_bt<0, 64><<<dim3(16, 32), 256, 0, stream>>>(Ob, Wot, (float*)d_out, 4096, 1024, 2048);
}

// Round 8
// 286.215 us; speedup vs baseline: 1.8718x; 1.0513x over previous
//
#include <hip/hip_runtime.h>
#include <math.h>

typedef __attribute__((ext_vector_type(8))) short short8;
typedef __attribute__((ext_vector_type(4))) float f32x4;
typedef __attribute__((ext_vector_type(4))) unsigned int uint4v;

#define HIDDEN 1024
#define QOUT 2048
#define KVOUT 1024
#define HD 128
#define TSEQ 2048

__device__ __forceinline__ float bf2f(unsigned short h) {
    union { unsigned int u; float f; } x; x.u = ((unsigned int)h) << 16; return x.f;
}
__device__ __forceinline__ unsigned short f2bf(float f) {
    union { float f; unsigned int u; } x; x.f = f;
    unsigned int r = (x.u + 0x7fffu + ((x.u >> 16) & 1u)) >> 16;
    return (unsigned short)r;
}
__device__ __forceinline__ unsigned int pk2bf(float lo, float hi) {
    return (unsigned int)f2bf(lo) | ((unsigned int)f2bf(hi) << 16);
}

// async global->LDS, 16B per lane; dest = wave-uniform base + lane*16
__device__ __forceinline__ void glds16(const unsigned short* g, unsigned short* l) {
    __builtin_amdgcn_global_load_lds(
        (const __attribute__((address_space(1))) unsigned int*)g,
        (__attribute__((address_space(3))) unsigned int*)l, 16, 0, 0);
}

// ---------------- prep: cast x->bf16  +  4 weight transposes (fp32 KxN -> bf16 NxK) ---------
__global__ __launch_bounds__(256) void prep(const float* __restrict__ x,
                                            const float* __restrict__ Wq,
                                            const float* __restrict__ Wk,
                                            const float* __restrict__ Wv,
                                            const float* __restrict__ Wo,
                                            unsigned short* __restrict__ xb,
                                            unsigned short* __restrict__ Wt,
                                            unsigned short* __restrict__ Wot) {
    int bid = blockIdx.x;
    int tid = threadIdx.x;
    if (bid < 4096) {  // cast: 1M float4
        int i = bid * 256 + tid;
        float4 v = *(const float4*)(x + (size_t)i * 4);
        unsigned short o[4] = {f2bf(v.x), f2bf(v.y), f2bf(v.z), f2bf(v.w)};
        *(unsigned long long*)(xb + (size_t)i * 4) = *(unsigned long long*)o;
        return;
    }
    bid -= 4096;
    const float* W; unsigned short* D; int K, N;
    if (bid < 512)       { W = Wq; D = Wt;                          K = 1024; N = 2048; }
    else if (bid < 768)  { bid -= 512;  W = Wk; D = Wt + (size_t)2048 * 1024; K = 1024; N = 1024; }
    else if (bid < 1024) { bid -= 768;  W = Wv; D = Wt + (size_t)3072 * 1024; K = 1024; N = 1024; }
    else                 { bid -= 1024; W = Wo; D = Wot;                      K = 2048; N = 1024; }
    __shared__ __attribute__((aligned(16))) unsigned short Ls[64 * 72];
    int ntiles = N >> 6;
    int kt = bid / ntiles, nt = bid - kt * ntiles;
    int k0 = kt * 64, n0 = nt * 64;
    for (int t = 0; t < 4; t++) {
        int idx = tid + t * 256;
        int r = idx >> 4, seg = idx & 15;
        float4 v = *(const float4*)(W + (size_t)(k0 + r) * N + n0 + seg * 4);
        int c = seg * 4;
        Ls[(c + 0) * 72 + r] = f2bf(v.x);
        Ls[(c + 1) * 72 + r] = f2bf(v.y);
        Ls[(c + 2) * 72 + r] = f2bf(v.z);
        Ls[(c + 3) * 72 + r] = f2bf(v.w);
    }
    __syncthreads();
    for (int t = 0; t < 2; t++) {
        int idx = tid + t * 256;
        int rr = idx >> 3, seg = idx & 7;
        uint4v v = *(const uint4v*)(Ls + rr * 72 + seg * 8);
        *(uint4v*)(D + (size_t)(n0 + rr) * K + k0 + seg * 8) = v;
    }
}

// ---------------- GEMM: C[M,N] = A[M,K](bf16) @ Bt[N,K]^T(bf16) ----------------
// Single-barrier double-buffered glds16 staging: prefetch(it+1) issued AFTER the
// barrier, so the next barrier's vmcnt(0) drain overlaps with this iteration's MFMA.
template <int OUT_BF16, int BN>
__global__ __launch_bounds__(256) void gemm_bt(const unsigned short* __restrict__ A,
                                               const unsigned short* __restrict__ Bt,
                                               void* __restrict__ Cout,
                                               int M, int N, int K) {
    constexpr int MT = (BN == 128) ? 4 : 2;
    __shared__ __attribute__((aligned(16))) unsigned short As[2][128 * 32];
    __shared__ __attribute__((aligned(16))) unsigned short Bs[2][BN * 32];
    const int tid = threadIdx.x;
    const int lane = tid & 63;
    const int warp = tid >> 6;
    const int ln = lane & 15;
    const int quad = lane >> 4;
    const int wm = (BN == 128) ? (warp >> 1) : warp;
    const int wn = (BN == 128) ? (warp & 1) : 0;
    const int m0 = blockIdx.y * 128;
    const int n0 = blockIdx.x * BN;

    const int srow = lane >> 2;
    const int schunk = (lane & 3) ^ (srow & 3);
    const unsigned short* Ag = A + (size_t)(m0 + warp * 16 + srow) * K + schunk * 8;
    const unsigned short* Bg = Bt + (size_t)(n0 + warp * 16 + srow) * K + schunk * 8;

    f32x4 acc[MT][4];
#pragma unroll
    for (int i = 0; i < MT; i++)
#pragma unroll
        for (int j = 0; j < 4; j++) acc[i][j] = (f32x4){0.f, 0.f, 0.f, 0.f};

    auto stage = [&](int k0, int bi) {
        glds16(Ag + k0, As[bi] + warp * 16 * 32);
        glds16(Ag + (size_t)64 * K + k0, As[bi] + warp * 16 * 32 + 64 * 32);
        glds16(Bg + k0, Bs[bi] + warp * 16 * 32);
        if (BN == 128) glds16(Bg + (size_t)64 * K + k0, Bs[bi] + warp * 16 * 32 + 64 * 32);
    };

    const int rq = quad ^ (ln & 3);   // swizzled read chunk
    const int KI = K >> 5;
    stage(0, 0);
    for (int it = 0; it < KI; it++) {
        __syncthreads();            // drains my glds for buf it&1
        if (it + 1 < KI) stage((it + 1) << 5, (it + 1) & 1);
        const unsigned short* Ab = As[it & 1];
        const unsigned short* Bb = Bs[it & 1];
        short8 af[MT], bf[4];
#pragma unroll
        for (int mt = 0; mt < MT; mt++)
            af[mt] = *(const short8*)(Ab + (wm * (MT * 16) + mt * 16 + ln) * 32 + rq * 8);
#pragma unroll
        for (int nt = 0; nt < 4; nt++)
            bf[nt] = *(const short8*)(Bb + (wn * 64 + nt * 16 + ln) * 32 + rq * 8);
#pragma unroll
        for (int mt = 0; mt < MT; mt++)
#pragma unroll
            for (int nt = 0; nt < 4; nt++)
                acc[mt][nt] = __builtin_amdgcn_mfma_f32_16x16x32_bf16(bf[nt], af[mt], acc[mt][nt], 0, 0, 0);
    }
#pragma unroll
    for (int mt = 0; mt < MT; mt++) {
        int row = m0 + wm * (MT * 16) + mt * 16 + ln;
#pragma unroll
        for (int nt = 0; nt < 4; nt++) {
            int colb = n0 + wn * 64 + nt * 16 + quad * 4;
            if (OUT_BF16) {
                unsigned long long pk =
                    (unsigned long long)pk2bf(acc[mt][nt][0], acc[mt][nt][1]) |
                    ((unsigned long long)pk2bf(acc[mt][nt][2], acc[mt][nt][3]) << 32);
                *(unsigned long long*)((unsigned short*)Cout + (size_t)row * N + colb) = pk;
            } else {
                *(f32x4*)((float*)Cout + (size_t)row * N + colb) = acc[mt][nt];
            }
        }
    }
}

// ---------------- fused norm_rope (blocks < 24576) + v_transpose (rest) ----------------
__global__ __launch_bounds__(256) void nrvt(const unsigned short* __restrict__ QKV,
                                            const float* __restrict__ qw,
                                            const float* __restrict__ kw,
                                            unsigned short* __restrict__ Q,
                                            unsigned short* __restrict__ Kb,
                                            unsigned short* __restrict__ Vt) {
    if (blockIdx.x < 24576) {
        int warp = threadIdx.x >> 6;
        int lane = threadIdx.x & 63;
        int gid = blockIdx.x * 4 + warp;
        int tok = gid / 24;
        int slot = gid - tok * 24;
        int b = tok >> 11, t = tok & 2047;
        const float* w;
        unsigned short* dst;
        int col0;
        if (slot < 16) {
            col0 = slot * HD;
            dst = Q + ((size_t)(b * 16 + slot) * TSEQ + t) * HD;
            w = qw;
        } else {
            int hk = slot - 16;
            col0 = QOUT + hk * HD;
            dst = Kb + ((size_t)(b * 8 + hk) * TSEQ + t) * HD;
            w = kw;
        }
        const unsigned short* row = QKV + (size_t)tok * 4096 + col0;
        float e0 = bf2f(row[lane]), e1 = bf2f(row[lane + 64]);
        float ss = e0 * e0 + e1 * e1;
        for (int off = 1; off < 64; off <<= 1) ss += __shfl_xor(ss, off);
        float rr = rsqrtf(ss * (1.0f / 128.0f) + 1e-6f);
        float n0 = e0 * rr * w[lane];
        float n1 = e1 * rr * w[lane + 64];
        float invf = __builtin_exp2f(-(float)lane * 0.20762050593045951f);
        float ang = (float)t * invf;
        float sf, cf;
        __sincosf(ang, &sf, &cf);
        dst[lane] = f2bf(n0 * cf - n1 * sf);
        dst[lane + 64] = f2bf(n1 * cf + n0 * sf);
        return;
    }
    // v_transpose
    __shared__ __attribute__((aligned(16))) unsigned short Ls[128 * 72];
    int bid = blockIdx.x - 24576;
    int tt = bid & 31, hk = (bid >> 5) & 7, b = bid >> 8;
    int t0 = tt * 64;
    int tid = threadIdx.x;
    const unsigned short* base = QKV + (size_t)(b * 2048 + t0) * 4096 + 3072 + hk * 128;
    for (int i = 0; i < 4; i++) {
        int idx = tid + i * 256;
        int r = idx >> 4, seg = idx & 15;
        uint4v v = *(const uint4v*)(base + (size_t)r * 4096 + seg * 8);
        unsigned short* pv = (unsigned short*)&v;
        int d = seg * 8;
        for (int jj = 0; jj < 8; jj++) Ls[(d + jj) * 72 + r] = pv[jj];
    }
    __syncthreads();
    unsigned short* out = Vt + (size_t)(b * 8 + hk) * 128 * 2048;
    for (int i = 0; i < 4; i++) {
        int idx = tid + i * 256;
        int d = idx >> 3, seg = idx & 7;
        uint4v v = *(const uint4v*)(Ls + d * 72 + seg * 8);
        *(uint4v*)(out + (size_t)d * 2048 + t0 + seg * 8) = v;
    }
}

// ---------------- flash attention v7: single-barrier double-buffered K/V ----------------
// grid (16 p, 32 b*h), 256 thr. Wave owns 16 rows of tile p (strip 0, active j<=p)
// and 16 rows of tile 31-p (strip 1, always active). Prefetch j+1 after the barrier.
__global__ __launch_bounds__(256, 2) void attn(const unsigned short* __restrict__ Q,
                                               const unsigned short* __restrict__ Kg,
                                               const unsigned short* __restrict__ Vt,
                                               unsigned short* __restrict__ Og) {
    __shared__ __attribute__((aligned(16))) unsigned short Ks[2][64 * 128];  // swizzled (kv, d)
    __shared__ __attribute__((aligned(16))) unsigned short Vs[2][128 * 64];  // swizzled (d, kv)
    __shared__ __attribute__((aligned(16))) unsigned short Ps[4][16 * 72];
    const int p = blockIdx.x;
    const int bh = blockIdx.y;
    const int b = bh >> 4, h = bh & 15, hk = h >> 1;
    const int tid = threadIdx.x;
    const int warp = tid >> 6, lane = tid & 63, ln = lane & 15, quad = lane >> 4;
    const int strip[2] = { p * 64 + warp * 16, (31 - p) * 64 + warp * 16 };
    const int jdiag[2] = { p, 31 - p };

    const unsigned short* Kbase = Kg + (size_t)(b * 8 + hk) * TSEQ * HD;
    const unsigned short* Vbase = Vt + (size_t)(b * 8 + hk) * HD * TSEQ;
    const unsigned short* Qh = Q + (size_t)(b * 16 + h) * TSEQ * HD;

    short8 qf[2][4];
#pragma unroll
    for (int st = 0; st < 2; st++)
#pragma unroll
        for (int kt = 0; kt < 4; kt++)
            qf[st][kt] = *(const short8*)(Qh + (size_t)(strip[st] + ln) * HD + kt * 32 + quad * 8);

    f32x4 o[2][8];
#pragma unroll
    for (int st = 0; st < 2; st++)
#pragma unroll
        for (int ot = 0; ot < 8; ot++) o[st][ot] = (f32x4){0.f, 0.f, 0.f, 0.f};
    float m_[2] = {-1e30f, -1e30f}, l_[2] = {0.f, 0.f};

    const int kr = lane >> 4;
    const int kc = lane & 15;
    const int vr = lane >> 3;
    const int vc = lane & 7;

    auto stage_kv = [&](int jt, int bi) {
        const int j0s = jt * 64;
        unsigned short* KsB = Ks[bi];
        unsigned short* VsB = Vs[bi];
#pragma unroll
        for (int c = 0; c < 4; c++) {   // K: LDS[r][c] = K[r][c ^ (r&15)]
            int row = warp * 16 + c * 4 + kr;
            glds16(Kbase + (size_t)(j0s + row) * HD + ((kc ^ (row & 15)) * 8),
                   KsB + (warp * 16 + c * 4) * 128);
        }
#pragma unroll
        for (int c = 0; c < 4; c++) {   // V^T: LDS[d][c] = V[d][c ^ (d&7)]
            int d = warp * 32 + c * 8 + vr;
            glds16(Vbase + (size_t)d * TSEQ + j0s + ((vc ^ (d & 7)) * 8),
                   VsB + (warp * 32 + c * 8) * 64);
        }
    };

    const float kscale = 0.12750580997495268f;  // (1/sqrt(128)) * log2(e)
    const int nT = 32 - p;
    stage_kv(0, 0);
    for (int j = 0; j < nT; j++) {
        __syncthreads();                 // drains my glds for buf j&1 (prev iter's prefetch)
        if (j + 1 < nT) stage_kv(j + 1, (j + 1) & 1);
        const unsigned short* KsC = Ks[j & 1];
        const unsigned short* VsC = Vs[j & 1];
        const bool act0 = (j <= jdiag[0]);
        // ---- QK^T for both strips, kf shared ----
        f32x4 s[2][4];
#pragma unroll
        for (int kb = 0; kb < 4; kb++) {
            s[0][kb] = (f32x4){0.f, 0.f, 0.f, 0.f};
            s[1][kb] = (f32x4){0.f, 0.f, 0.f, 0.f};
        }
#pragma unroll
        for (int kt = 0; kt < 4; kt++) {
            short8 kf[4];
#pragma unroll
            for (int kb = 0; kb < 4; kb++)
                kf[kb] = *(const short8*)(KsC + (kb * 16 + ln) * 128 + (((kt * 4 + quad) ^ ln) * 8));
#pragma unroll
            for (int kb = 0; kb < 4; kb++)
                s[1][kb] = __builtin_amdgcn_mfma_f32_16x16x32_bf16(kf[kb], qf[1][kt], s[1][kb], 0, 0, 0);
            if (act0)
#pragma unroll
                for (int kb = 0; kb < 4; kb++)
                    s[0][kb] = __builtin_amdgcn_mfma_f32_16x16x32_bf16(kf[kb], qf[0][kt], s[0][kb], 0, 0, 0);
        }
        // ---- softmax + P staging per strip (constant bounds, st==0 guarded) ----
        short8 pf[2][2];
        float al[2] = {1.f, 1.f};
#pragma unroll
        for (int st = 0; st < 2; st++) {
            if (st == 0 && !act0) continue;
            float mx = -1e30f;
            if (j == jdiag[st]) {
                const int qloc = warp * 16 + ln;
#pragma unroll
                for (int kb = 0; kb < 4; kb++)
#pragma unroll
                    for (int r = 0; r < 4; r++) {
                        int kvloc = kb * 16 + quad * 4 + r;
                        float v = s[st][kb][r] * kscale;
                        v = (kvloc > qloc) ? -1e30f : v;
                        s[st][kb][r] = v;
                        mx = fmaxf(mx, v);
                    }
            } else {
#pragma unroll
                for (int kb = 0; kb < 4; kb++)
#pragma unroll
                    for (int r = 0; r < 4; r++) {
                        float v = s[st][kb][r] * kscale;
                        s[st][kb][r] = v;
                        mx = fmaxf(mx, v);
                    }
            }
            mx = fmaxf(mx, __shfl_xor(mx, 16));
            mx = fmaxf(mx, __shfl_xor(mx, 32));
            float mn = fmaxf(m_[st], mx);
            al[st] = __builtin_exp2f(m_[st] - mn);
            float sum = 0.f;
#pragma unroll
            for (int kb = 0; kb < 4; kb++)
#pragma unroll
                for (int r = 0; r < 4; r++) {
                    float pv = __builtin_exp2f(s[st][kb][r] - mn);
                    s[st][kb][r] = pv;
                    sum += pv;
                }
            sum += __shfl_xor(sum, 16);
            sum += __shfl_xor(sum, 32);
            m_[st] = mn;
            l_[st] = l_[st] * al[st] + sum;
#pragma unroll
            for (int kb = 0; kb < 4; kb++) {
                unsigned long long pk =
                    (unsigned long long)pk2bf(s[st][kb][0], s[st][kb][1]) |
                    ((unsigned long long)pk2bf(s[st][kb][2], s[st][kb][3]) << 32);
                *(unsigned long long*)(&Ps[warp][ln * 72 + kb * 16 + quad * 4]) = pk;
            }
            pf[st][0] = *(const short8*)(&Ps[warp][ln * 72 + quad * 8]);
            pf[st][1] = *(const short8*)(&Ps[warp][ln * 72 + 32 + quad * 8]);
        }
        // ---- rescale O (per-lane alpha, q = ln) ----
        if (act0 && __any(al[0] != 1.0f))
#pragma unroll
            for (int ot = 0; ot < 8; ot++)
#pragma unroll
                for (int r = 0; r < 4; r++) o[0][ot][r] *= al[0];
        if (__any(al[1] != 1.0f))
#pragma unroll
            for (int ot = 0; ot < 8; ot++)
#pragma unroll
                for (int r = 0; r < 4; r++) o[1][ot][r] *= al[1];
        // ---- PV, vf shared across strips; operand-swapped (O: col=q=ln, rows=d) ----
#pragma unroll
        for (int ot = 0; ot < 8; ot++) {
            short8 vf0 = *(const short8*)(VsC + (ot * 16 + ln) * 64 + ((quad ^ (ln & 7)) * 8));
            short8 vf1 = *(const short8*)(VsC + (ot * 16 + ln) * 64 + (((4 + quad) ^ (ln & 7)) * 8));
            o[1][ot] = __builtin_amdgcn_mfma_f32_16x16x32_bf16(vf0, pf[1][0], o[1][ot], 0, 0, 0);
            o[1][ot] = __builtin_amdgcn_mfma_f32_16x16x32_bf16(vf1, pf[1][1], o[1][ot], 0, 0, 0);
            if (act0) {
                o[0][ot] = __builtin_amdgcn_mfma_f32_16x16x32_bf16(vf0, pf[0][0], o[0][ot], 0, 0, 0);
                o[0][ot] = __builtin_amdgcn_mfma_f32_16x16x32_bf16(vf1, pf[0][1], o[0][ot], 0, 0, 0);
            }
        }
    }
    // epilogue: lane has q = strip+ln; regs are 4 consecutive d -> 8B stores
#pragma unroll
    for (int st = 0; st < 2; st++) {
        float inv = 1.0f / l_[st];
        size_t rowoff = ((size_t)(b * TSEQ + strip[st] + ln)) * QOUT + h * 128 + quad * 4;
#pragma unroll
        for (int ot = 0; ot < 8; ot++) {
            unsigned long long pk =
                (unsigned long long)pk2bf(o[st][ot][0] * inv, o[st][ot][1] * inv) |
                ((unsigned long long)pk2bf(o[st][ot][2] * inv, o[st][ot][3] * inv) << 32);
            *(unsigned long long*)(Og + rowoff + ot * 16) = pk;
        }
    }
}

extern "C" void kernel_launch(void* const* d_in, const int* in_sizes, int n_in,
                              void* d_out, int out_size, void* d_ws, size_t ws_size,
                              hipStream_t stream) {
    (void)in_sizes; (void)n_in; (void)out_size;
    const float* x  = (const float*)d_in[0];
    const float* Wq = (const float*)d_in[1];
    const float* Wk = (const float*)d_in[2];
    const float* Wv = (const float*)d_in[3];
    const float* Wo = (const float*)d_in[4];
    const float* qw = (const float*)d_in[5];
    const float* kw = (const float*)d_in[6];

    char* ws = (char*)d_ws;
    const size_t MB = 1024 * 1024;
    unsigned short* Wt   = (unsigned short*)(ws);            // 8 MB
    unsigned short* Wot  = (unsigned short*)(ws + 8 * MB);   // 4 MB
    unsigned short* QKVb = (unsigned short*)(ws + 12 * MB);  // 32 MB (bf16)
    unsigned short* xb   = (unsigned short*)(ws + 44 * MB);  // 8 MB
    unsigned short* Qb   = (unsigned short*)(ws + 52 * MB);  // 16 MB
    unsigned short* Kb   = (unsigned short*)(ws + 68 * MB);  // 8 MB
    unsigned short* Vtb  = (unsigned short*)(ws + 76 * MB);  // 8 MB
    unsigned short* Ob   = (unsigned short*)(ws + 84 * MB);  // 16 MB
    if (ws_size < 100 * MB) return;

    prep<<<dim3(5632), 256, 0, stream>>>(x, Wq, Wk, Wv, Wo, xb, Wt, Wot);
    gemm_bt<1, 128><<<dim3(32, 32), 256, 0, stream>>>(xb, Wt, QKVb, 4096, 4096, 1024);
    nrvt<<<dim3(25088), 256, 0, stream>>>(QKVb, qw, kw, Qb, Kb, Vtb);
    attn<<<dim3(16, 32), 256, 0, stream>>>(Qb, Kb, Vtb, Ob);
    gemm_bt<0, 64><<<dim3(16, 32), 256, 0, stream>>>(Ob, Wot, (float*)d_out, 4096, 1024, 2048);
}